// Round 1
// baseline (326.144 us; speedup 1.0000x reference)
//
#include <hip/hip_runtime.h>

// MSE-sum loss: out[0] = 0.5 * sum((a[i]-b[i])^2), n = 40e6 fp32 per input.
// Memory-bound: 320 MB read -> ~51 us floor at 6.3 TB/s.

__global__ __launch_bounds__(256) void mse_kernel(const float* __restrict__ a,
                                                  const float* __restrict__ b,
                                                  float* __restrict__ out,
                                                  long n) {
    const long n4 = n >> 2;                 // float4 groups
    const long idx = (long)blockIdx.x * blockDim.x + threadIdx.x;
    const long stride = (long)gridDim.x * blockDim.x;

    const float4* __restrict__ a4 = (const float4*)a;
    const float4* __restrict__ b4 = (const float4*)b;

    float acc = 0.0f;
    for (long i = idx; i < n4; i += stride) {
        float4 x = a4[i];
        float4 y = b4[i];
        float d0 = x.x - y.x;
        float d1 = x.y - y.y;
        float d2 = x.z - y.z;
        float d3 = x.w - y.w;
        acc += d0 * d0 + d1 * d1 + d2 * d2 + d3 * d3;
    }

    // scalar tail (n not multiple of 4) — handled by first threads only
    const long tail_start = n4 << 2;
    if (idx < (n - tail_start)) {
        float d = a[tail_start + idx] - b[tail_start + idx];
        acc += d * d;
    }

    // wave-64 shuffle reduction
    #pragma unroll
    for (int off = 32; off > 0; off >>= 1)
        acc += __shfl_down(acc, off, 64);

    __shared__ float wave_sums[4];          // 256 threads / 64 lanes
    const int lane = threadIdx.x & 63;
    const int wid  = threadIdx.x >> 6;
    if (lane == 0) wave_sums[wid] = acc;
    __syncthreads();

    if (threadIdx.x == 0) {
        float s = wave_sums[0] + wave_sums[1] + wave_sums[2] + wave_sums[3];
        atomicAdd(out, 0.5f * s);           // device-scope by default on CDNA
    }
}

extern "C" void kernel_launch(void* const* d_in, const int* in_sizes, int n_in,
                              void* d_out, int out_size, void* d_ws, size_t ws_size,
                              hipStream_t stream) {
    const float* a = (const float*)d_in[0];
    const float* b = (const float*)d_in[1];
    float* out = (float*)d_out;
    const long n = (long)in_sizes[0];       // 40,000,000

    // d_out is re-poisoned to 0xAA before every timed launch — zero it first.
    hipMemsetAsync(d_out, 0, sizeof(float), stream);

    const int block = 256;
    const int grid = 2048;                  // 8 blocks/CU worth of waves; grid-stride covers n
    mse_kernel<<<grid, block, 0, stream>>>(a, b, out, n);
}

// Round 2
// 320.632 us; speedup vs baseline: 1.0172x; 1.0172x over previous
//
#include <hip/hip_runtime.h>

// MSE-sum loss: out[0] = 0.5 * sum((a[i]-b[i])^2), n = 40e6 fp32 per input.
// Memory/latency-bound. R1 showed 116us with only 2 loads in flight per wave
// (VALUBusy 3%, hbm 17%): unroll grid-stride 4x -> 8 independent 16B loads
// in flight per wave per iteration.

__global__ __launch_bounds__(256) void mse_kernel(const float* __restrict__ a,
                                                  const float* __restrict__ b,
                                                  float* __restrict__ out,
                                                  long n) {
    const long n4 = n >> 2;                 // float4 groups (n divisible by 4 here)
    const long idx = (long)blockIdx.x * blockDim.x + threadIdx.x;
    const long stride = (long)gridDim.x * blockDim.x;

    const float4* __restrict__ a4 = (const float4*)a;
    const float4* __restrict__ b4 = (const float4*)b;

    float acc = 0.0f;

    long i = idx;
    const long step = stride * 4;
    // main unrolled loop: 8 independent global_load_dwordx4 issued per iter
    for (; i + 3 * stride < n4; i += step) {
        float4 x0 = a4[i];
        float4 x1 = a4[i + stride];
        float4 x2 = a4[i + 2 * stride];
        float4 x3 = a4[i + 3 * stride];
        float4 y0 = b4[i];
        float4 y1 = b4[i + stride];
        float4 y2 = b4[i + 2 * stride];
        float4 y3 = b4[i + 3 * stride];

        float d;
        d = x0.x - y0.x; acc += d * d;
        d = x0.y - y0.y; acc += d * d;
        d = x0.z - y0.z; acc += d * d;
        d = x0.w - y0.w; acc += d * d;
        d = x1.x - y1.x; acc += d * d;
        d = x1.y - y1.y; acc += d * d;
        d = x1.z - y1.z; acc += d * d;
        d = x1.w - y1.w; acc += d * d;
        d = x2.x - y2.x; acc += d * d;
        d = x2.y - y2.y; acc += d * d;
        d = x2.z - y2.z; acc += d * d;
        d = x2.w - y2.w; acc += d * d;
        d = x3.x - y3.x; acc += d * d;
        d = x3.y - y3.y; acc += d * d;
        d = x3.z - y3.z; acc += d * d;
        d = x3.w - y3.w; acc += d * d;
    }
    // remainder grid-stride loop
    for (; i < n4; i += stride) {
        float4 x = a4[i];
        float4 y = b4[i];
        float d0 = x.x - y.x;
        float d1 = x.y - y.y;
        float d2 = x.z - y.z;
        float d3 = x.w - y.w;
        acc += d0 * d0 + d1 * d1 + d2 * d2 + d3 * d3;
    }

    // scalar tail (n not multiple of 4) — empty for n=40e6 but kept for safety
    const long tail_start = n4 << 2;
    if (idx < (n - tail_start)) {
        float d = a[tail_start + idx] - b[tail_start + idx];
        acc += d * d;
    }

    // wave-64 shuffle reduction
    #pragma unroll
    for (int off = 32; off > 0; off >>= 1)
        acc += __shfl_down(acc, off, 64);

    __shared__ float wave_sums[4];          // 256 threads / 64 lanes
    const int lane = threadIdx.x & 63;
    const int wid  = threadIdx.x >> 6;
    if (lane == 0) wave_sums[wid] = acc;
    __syncthreads();

    if (threadIdx.x == 0) {
        float s = wave_sums[0] + wave_sums[1] + wave_sums[2] + wave_sums[3];
        atomicAdd(out, 0.5f * s);           // device-scope by default on CDNA
    }
}

extern "C" void kernel_launch(void* const* d_in, const int* in_sizes, int n_in,
                              void* d_out, int out_size, void* d_ws, size_t ws_size,
                              hipStream_t stream) {
    const float* a = (const float*)d_in[0];
    const float* b = (const float*)d_in[1];
    float* out = (float*)d_out;
    const long n = (long)in_sizes[0];       // 40,000,000

    // d_out is re-poisoned to 0xAA before every timed launch — zero it first.
    hipMemsetAsync(d_out, 0, sizeof(float), stream);

    const int block = 256;
    const int grid = 2048;                  // 8192 waves = full 256 CU x 32 wave capacity
    mse_kernel<<<grid, block, 0, stream>>>(a, b, out, n);
}